// Round 9
// baseline (11572.936 us; speedup 1.0000x reference)
//
#include <hip/hip_runtime.h>
#include <stdint.h>
#include <stddef.h>

// Row-parallel linear: C[M][N] = A[M][K] * W[N][K]^T + bias
// M = SEQ*BATCH = 8192, N = D_MODEL = 4096, K = D_FF = 16384
#define M_DIM 8192
#define N_DIM 4096
#define K_DIM 16384

#define BM 256
#define BN 256
#define BK 64
#define NTHR 512                  // 8 waves: 2 (M) x 4 (N)
#define K_TILES (K_DIM / BK)      // 256

typedef __attribute__((ext_vector_type(8))) short bf16x8;   // 8 bf16 = 4 VGPRs
typedef __attribute__((ext_vector_type(4))) float f32x4;    // MFMA C/D

#define AS1 __attribute__((address_space(1)))
#define AS3 __attribute__((address_space(3)))

__device__ __forceinline__ unsigned short f2bf(float f) {
  union { float f; unsigned u; } x; x.f = f;
  unsigned r = x.u + 0x7fffu + ((x.u >> 16) & 1u);
  return (unsigned short)(r >> 16);
}

// ------------- pass 1: fused fp32 -> bf16 conversion (A then W) ---------------
__global__ void cvt2_f32_bf16(const float* __restrict__ inA,
                              unsigned short* __restrict__ outA, long nA4,
                              const float* __restrict__ inW,
                              unsigned short* __restrict__ outW, long nW4) {
  long idx = (long)blockIdx.x * blockDim.x + threadIdx.x;
  long stride = (long)gridDim.x * blockDim.x;
  const float4* a4 = (const float4*)inA;
  ushort4* oa4 = (ushort4*)outA;
  for (long i = idx; i < nA4; i += stride) {
    float4 v = a4[i];
    ushort4 o;
    o.x = f2bf(v.x); o.y = f2bf(v.y); o.z = f2bf(v.z); o.w = f2bf(v.w);
    oa4[i] = o;
  }
  const float4* w4 = (const float4*)inW;
  ushort4* ow4 = (ushort4*)outW;
  for (long i = idx; i < nW4; i += stride) {
    float4 v = w4[i];
    ushort4 o;
    o.x = f2bf(v.x); o.y = f2bf(v.y); o.z = f2bf(v.z); o.w = f2bf(v.w);
    ow4[i] = o;
  }
}

// ---------------- pass 2: 256x256 bf16 GEMM, 8-phase, deep tail-reads ---------
// 8 phases = 2 K-tiles (u->buf0, v->buf1), ONE barrier per phase (proven best).
// ALL ds_reads are issued >=1 barrier before consumption ("tail" position,
// after the phase's MFMA, into registers that just died):
//   ph2-tail : af1(u) [8]        -> consumed ph3/ph4, drained by ph3 LGKM0
//   ph4-tail : af0+bf01+bf23 (v) [16]  (legal: ph4's vmcnt(4) FIFO-completes
//              exactly tile v)   -> consumed ph5..ph8, drained by ph5 LGKM0
//   ph6-tail : af1(v) [8]        -> consumed ph7/ph8, drained by ph7 LGKM0
//   ph8-tail : af0+bf01+bf23 (u+2) [16] -> consumed next ph1.., next-ph1 LGKM0
// => ph1/ph3/ph5/ph7 issue ZERO fresh reads; LGKM0 only at odd phases (drains
// one-phase-old batches, ~free). Stage placement (slot-liveness proven r5/r6):
// ph1:A0(v) ph2:A1(v) ph3:B0(u+2) ph4:B1(u+2) ph5:A0(u+2) ph6:A1(u+2)
// ph7:B0(v+2) ph8:B1(v+2). Every stage-issue sits >=1 barrier after the LGKM0
// that drained its slot's last readers (WAR certified, no timing margins).
#define BAR()    __builtin_amdgcn_s_barrier()
#define SCHED0() __builtin_amdgcn_sched_barrier(0)
#define WAIT_LGKM0() do { asm volatile("s_waitcnt lgkmcnt(0)" ::: "memory"); \
                          __builtin_amdgcn_sched_barrier(0); } while (0)
#define VMCNT(N) asm volatile("s_waitcnt vmcnt(" #N ")" ::: "memory")

#define MFMA_QUAD(MQ, NP)                                                      \
  do {                                                                         \
    __builtin_amdgcn_s_setprio(1);                                             \
    _Pragma("unroll") for (int mi = 0; mi < 4; ++mi)                           \
      _Pragma("unroll") for (int nn = 0; nn < 2; ++nn)                         \
        _Pragma("unroll") for (int ks = 0; ks < 2; ++ks)                       \
          acc[(MQ)*4 + mi][(NP)*2 + nn] =                                      \
              __builtin_amdgcn_mfma_f32_16x16x32_bf16(                         \
                  af[mi][ks], bf[(NP)*2 + nn][ks],                             \
                  acc[(MQ)*4 + mi][(NP)*2 + nn], 0, 0, 0);                     \
    __builtin_amdgcn_s_setprio(0);                                             \
  } while (0)

__global__ __launch_bounds__(NTHR, 2)
void gemm256(const unsigned short* __restrict__ A,
             const unsigned short* __restrict__ W,
             const float* __restrict__ bias, float* __restrict__ C) {
  __shared__ unsigned short smA[2][BM * BK];   // 2 x 32 KiB
  __shared__ unsigned short smB[2][BN * BK];   // 2 x 32 KiB

  const int tid  = threadIdx.x;
  const int wave = tid >> 6;
  const int lane = tid & 63;
  const int wr = wave >> 2;          // 0..1  (M waves, 128 rows each)
  const int wc = wave & 3;           // 0..3  (N waves, 64 cols each)
  const int g  = lane >> 4;          // frag k-group
  const int xr = (lane & 7) << 4;    // read-side swizzle term

  int csw[2];
  csw[0] = (g * 16) ^ xr;
  csw[1] = (64 + g * 16) ^ xr;

  // XCD-aware bijective swizzle; nwg = 512 (divisible by 8)
  const int nbn = N_DIM / BN;                  // 16
  const int nwg = (M_DIM / BM) * nbn;          // 512
  const int bid = blockIdx.x;
  const int swz = (bid & 7) * (nwg >> 3) + (bid >> 3);
  const int bm = swz / nbn, bn = swz % nbn;
  const int bmBase = bm * BM, bnBase = bn * BN;

  // per-lane pre-swizzled global source offset (elements):
  // lane l -> dest row +(l>>3), 16B slot l&7 holds global slot (l&7)^((l>>3)&7)
  const size_t laneOff = (size_t)(lane >> 3) * K_DIM +
                         (size_t)(((lane & 7) ^ ((lane >> 3) & 7)) * 8);

  const unsigned short* aStage = A + (size_t)bmBase * K_DIM + laneOff;
  const unsigned short* bStage = W + (size_t)bnBase * K_DIM + laneOff;

  f32x4 acc[8][4];
  const f32x4 z = {0.f, 0.f, 0.f, 0.f};
#pragma unroll
  for (int m = 0; m < 8; ++m)
#pragma unroll
    for (int n = 0; n < 4; ++n) acc[m][n] = z;

  bf16x8 af[4][2];   // current m-quad fragments (mq0/mq1 share the slot)
  bf16x8 bf[4][2];   // all 4 n fragments (bf01 = n0:1, bf23 = n2:3)

  // stage one half-tile (16 KiB = 8 waves x 2 instr x 64 lanes x 16 B)
  auto stageHalfA = [&](int h, int buf, size_t kOff) {
#pragma unroll
    for (int j = 0; j < 2; ++j) {
      const int row0 = h * 128 + wave * 16 + j * 8;     // wave-uniform base row
      const unsigned short* src = aStage + (size_t)row0 * K_DIM + kOff;
      unsigned short* dst = &smA[buf][row0 * BK];
      __builtin_amdgcn_global_load_lds((AS1 void*)src, (AS3 void*)dst, 16, 0, 0);
    }
  };
  auto stageHalfB = [&](int h, int buf, size_t kOff) {
#pragma unroll
    for (int j = 0; j < 2; ++j) {
      const int row0 = h * 128 + wave * 16 + j * 8;
      const unsigned short* src = bStage + (size_t)row0 * K_DIM + kOff;
      unsigned short* dst = &smB[buf][row0 * BK];
      __builtin_amdgcn_global_load_lds((AS1 void*)src, (AS3 void*)dst, 16, 0, 0);
    }
  };

  const char* aRd[2] = {
      (const char*)&smA[0][0] + (wr * 128 + (lane & 15)) * 128,
      (const char*)&smA[1][0] + (wr * 128 + (lane & 15)) * 128};
  const char* bRd[2] = {
      (const char*)&smB[0][0] + (wc * 64 + (lane & 15)) * 128,
      (const char*)&smB[1][0] + (wc * 64 + (lane & 15)) * 128};

  auto readA = [&](const char* p, int mq) {
#pragma unroll
    for (int mi = 0; mi < 4; ++mi)
#pragma unroll
      for (int ks = 0; ks < 2; ++ks)
        af[mi][ks] = *(const bf16x8*)(p + (mq * 64 + mi * 16) * 128 + csw[ks]);
  };
  auto readB = [&](const char* p, int np) {
#pragma unroll
    for (int nn = 0; nn < 2; ++nn)
#pragma unroll
      for (int ks = 0; ks < 2; ++ks)
        bf[np * 2 + nn][ks] =
            *(const bf16x8*)(p + (np * 32 + nn * 16) * 128 + csw[ks]);
  };

  // one iteration = 2 K-tiles: u (buf0), v=u+1 (buf1). full=false: final iter.
  auto iter_body = [&](size_t ku, bool full) {
    const size_t kv = ku + BK, ku2 = ku + 2 * BK, kv2 = ku + 3 * BK;

    // ph1: stage A0(v); BAR; drain prev-ph8 tail; MFMA(u;00)
    stageHalfA(0, 1, kv);
    BAR(); WAIT_LGKM0();
    MFMA_QUAD(0, 0);

    // ph2: stage A1(v); BAR; MFMA(u;01) [bf23(u) from prev-ph8 tail, drained];
    //      tail: af1(u)
    stageHalfA(1, 1, kv);
    BAR(); SCHED0();
    MFMA_QUAD(0, 1);
    SCHED0();
    readA(aRd[0], 1);                              // 8 ds_reads (tail)

    // ph3: stage B0(u+2); BAR; drain ph2-tail; MFMA(u;11)
    if (full) stageHalfB(0, 0, ku2);
    BAR(); WAIT_LGKM0();
    MFMA_QUAD(1, 1);

    // ph4: stage B1(u+2); vmcnt(4) -> tile v fully resident; BAR; MFMA(u;10);
    //      tail: ALL of v (af0+bf01+bf23)
    if (full) {
      stageHalfB(1, 0, ku2);
      VMCNT(4);
    } else {
      VMCNT(0);
    }
    BAR(); SCHED0();
    MFMA_QUAD(1, 0);
    SCHED0();
    readA(aRd[1], 0); readB(bRd[1], 0); readB(bRd[1], 1);   // 16 ds_reads (tail)

    // ph5: stage A0(u+2); BAR; drain ph4-tail; MFMA(v;00)
    if (full) stageHalfA(0, 0, ku2);
    BAR(); WAIT_LGKM0();
    MFMA_QUAD(0, 0);

    // ph6: stage A1(u+2); BAR; MFMA(v;01); tail: af1(v)
    if (full) stageHalfA(1, 0, ku2);
    BAR(); SCHED0();
    MFMA_QUAD(0, 1);
    SCHED0();
    readA(aRd[1], 1);                              // 8 ds_reads (tail)

    // ph7: stage B0(v+2); BAR; drain ph6-tail; MFMA(v;11)
    if (full) stageHalfB(0, 1, kv2);
    BAR(); WAIT_LGKM0();
    MFMA_QUAD(1, 1);

    // ph8: stage B1(v+2); vmcnt(4) -> tile u+2 fully resident; BAR; MFMA(v;10);
    //      tail: ALL of u+2 (af0+bf01+bf23) for next ph1
    if (full) {
      stageHalfB(1, 1, kv2);
      VMCNT(4);
    }
    BAR(); SCHED0();
    MFMA_QUAD(1, 0);
    if (full) {
      SCHED0();
      readA(aRd[0], 0); readB(bRd[0], 0); readB(bRd[0], 1); // 16 ds_reads (tail)
    }
  };

  // ---- prologue: 6 half-tiles; vmcnt(4) -> tile0 resident, B(1) in flight ----
  stageHalfB(0, 0, 0); stageHalfB(1, 0, 0);
  stageHalfA(0, 0, 0); stageHalfA(1, 0, 0);
  stageHalfB(0, 1, BK); stageHalfB(1, 1, BK);
  VMCNT(4);
  BAR(); SCHED0();
  readA(aRd[0], 0); readB(bRd[0], 0); readB(bRd[0], 1);  // "prev-ph8" tail reads

  size_t ku = 0;
  for (int J = 0; J < K_TILES / 2 - 1; ++J) {   // 127 steady iterations
    iter_body(ku, true);
    ku += 2 * BK;
  }
  iter_body(ku, false);                          // tiles 254,255: drain

  // ---- epilogue: C = acc + bias. C/D layout: col=lane&15, row=(lane>>4)*4+j
  const int crow0 = bmBase + wr * 128 + ((lane >> 4) << 2);
  const int ccol0 = bnBase + wc * 64 + (lane & 15);
#pragma unroll
  for (int n = 0; n < 4; ++n) {
    const float bv = bias[ccol0 + n * 16];
#pragma unroll
    for (int mi = 0; mi < 8; ++mi) {
      const size_t base = (size_t)(crow0 + mi * 16) * N_DIM + (ccol0 + n * 16);
#pragma unroll
      for (int j = 0; j < 4; ++j)
        C[base + (size_t)j * N_DIM] = acc[mi][n][j] + bv;
    }
  }
}

// ---------------- fallback: fused-cvt 128x128 GEMM (ws too small) -------------
__global__ __launch_bounds__(256)
void gemm_fallback(const float* __restrict__ Af, const float* __restrict__ Wf,
                   const float* __restrict__ bias, float* __restrict__ C) {
  __shared__ __align__(16) unsigned short sA[128 * 64];
  __shared__ __align__(16) unsigned short sB[128 * 64];
  const int tid = threadIdx.x, wave = tid >> 6, lane = tid & 63;
  const int wr = wave >> 1, wc = wave & 1;
  const int nbn = N_DIM / 128, nwg = (M_DIM / 128) * nbn;
  const int swz = (blockIdx.x & 7) * (nwg >> 3) + (blockIdx.x >> 3);
  const int bm = swz / nbn, bn = swz % nbn;
  f32x4 acc[4][4];
  const f32x4 z = {0.f, 0.f, 0.f, 0.f};
#pragma unroll
  for (int m = 0; m < 4; ++m)
#pragma unroll
    for (int n = 0; n < 4; ++n) acc[m][n] = z;
  for (int kt = 0; kt < K_DIM / 64; ++kt) {
    const int k0 = kt * 64;
    const int row2 = tid >> 1, ch = (tid & 1) * 32;
    const float* sa = Af + (size_t)(bm * 128 + row2) * K_DIM + k0 + ch;
    const float* sb = Wf + (size_t)(bn * 128 + row2) * K_DIM + k0 + ch;
    unsigned short* da = sA + row2 * 64 + ch;
    unsigned short* db = sB + row2 * 64 + ch;
#pragma unroll
    for (int j = 0; j < 8; ++j) {
      float4 v = *(const float4*)(sa + j * 4);
      ushort4 o; o.x = f2bf(v.x); o.y = f2bf(v.y); o.z = f2bf(v.z); o.w = f2bf(v.w);
      *(ushort4*)(da + j * 4) = o;
      float4 w = *(const float4*)(sb + j * 4);
      ushort4 p; p.x = f2bf(w.x); p.y = f2bf(w.y); p.z = f2bf(w.z); p.w = f2bf(w.w);
      *(ushort4*)(db + j * 4) = p;
    }
    __syncthreads();
#pragma unroll
    for (int ks = 0; ks < 2; ++ks) {
      bf16x8 a4[4], b4[4];
#pragma unroll
      for (int m = 0; m < 4; ++m)
        a4[m] = *(const bf16x8*)(sA + (wr * 64 + m * 16 + (lane & 15)) * 64 +
                                 ks * 32 + (lane >> 4) * 8);
#pragma unroll
      for (int n = 0; n < 4; ++n)
        b4[n] = *(const bf16x8*)(sB + (wc * 64 + n * 16 + (lane & 15)) * 64 +
                                 ks * 32 + (lane >> 4) * 8);
#pragma unroll
      for (int m = 0; m < 4; ++m)
#pragma unroll
        for (int n = 0; n < 4; ++n)
          acc[m][n] = __builtin_amdgcn_mfma_f32_16x16x32_bf16(a4[m], b4[n],
                                                              acc[m][n], 0, 0, 0);
    }
    __syncthreads();
  }
  const int crow = bm * 128 + wr * 64 + ((lane >> 4) << 2);
  const int ccol = bn * 128 + wc * 64 + (lane & 15);
#pragma unroll
  for (int n = 0; n < 4; ++n) {
    const float bv = bias[ccol + n * 16];
#pragma unroll
    for (int m = 0; m < 4; ++m) {
      const size_t base = (size_t)(crow + m * 16) * N_DIM + (ccol + n * 16);
#pragma unroll
      for (int j = 0; j < 4; ++j) C[base + (size_t)j * N_DIM] = acc[m][n][j] + bv;
    }
  }
}

// ------------------------------ launcher --------------------------------------
extern "C" void kernel_launch(void* const* d_in, const int* in_sizes, int n_in,
                              void* d_out, int out_size, void* d_ws, size_t ws_size,
                              hipStream_t stream) {
  const float* A    = (const float*)d_in[0];   // [8192, 16384] fp32
  const float* Wt   = (const float*)d_in[1];   // [4096, 16384] fp32
  const float* bias = (const float*)d_in[2];   // [4096] fp32
  float* out = (float*)d_out;                  // [8192, 4096] fp32

  const size_t elemsA = (size_t)M_DIM * K_DIM;
  const size_t elemsW = (size_t)N_DIM * K_DIM;
  const size_t need = (elemsA + elemsW) * sizeof(unsigned short);  // 384 MiB

  if (ws_size >= need) {
    unsigned short* wsA = (unsigned short*)d_ws;
    unsigned short* wsW = wsA + elemsA;
    cvt2_f32_bf16<<<2048, 256, 0, stream>>>(A, wsA, (long)(elemsA / 4),
                                            Wt, wsW, (long)(elemsW / 4));
    const int ngrid = (M_DIM / BM) * (N_DIM / BN);  // 512
    gemm256<<<ngrid, NTHR, 0, stream>>>(wsA, wsW, bias, out);
  } else {
    const int ngrid = (M_DIM / 128) * (N_DIM / 128);
    gemm_fallback<<<ngrid, 256, 0, stream>>>(A, Wt, bias, out);
  }
}

// Round 10
// 1131.117 us; speedup vs baseline: 10.2314x; 10.2314x over previous
//
#include <hip/hip_runtime.h>
#include <stdint.h>
#include <stddef.h>

// Row-parallel linear: C[M][N] = A[M][K] * W[N][K]^T + bias
// M = SEQ*BATCH = 8192, N = D_MODEL = 4096, K = D_FF = 16384
#define M_DIM 8192
#define N_DIM 4096
#define K_DIM 16384

#define BM 256
#define BN 256
#define BK 64
#define NTHR 512                  // 8 waves: 2 (M) x 4 (N)
#define K_TILES (K_DIM / BK)      // 256

typedef __attribute__((ext_vector_type(8))) short bf16x8;   // 8 bf16 = 4 VGPRs
typedef __attribute__((ext_vector_type(4))) float f32x4;    // MFMA C/D

#define AS1 __attribute__((address_space(1)))
#define AS3 __attribute__((address_space(3)))

__device__ __forceinline__ unsigned short f2bf(float f) {
  union { float f; unsigned u; } x; x.f = f;
  unsigned r = x.u + 0x7fffu + ((x.u >> 16) & 1u);
  return (unsigned short)(r >> 16);
}

// ------------- pass 1: fused fp32 -> bf16 conversion (A then W) ---------------
__global__ void cvt2_f32_bf16(const float* __restrict__ inA,
                              unsigned short* __restrict__ outA, long nA4,
                              const float* __restrict__ inW,
                              unsigned short* __restrict__ outW, long nW4) {
  long idx = (long)blockIdx.x * blockDim.x + threadIdx.x;
  long stride = (long)gridDim.x * blockDim.x;
  const float4* a4 = (const float4*)inA;
  ushort4* oa4 = (ushort4*)outA;
  for (long i = idx; i < nA4; i += stride) {
    float4 v = a4[i];
    ushort4 o;
    o.x = f2bf(v.x); o.y = f2bf(v.y); o.z = f2bf(v.z); o.w = f2bf(v.w);
    oa4[i] = o;
  }
  const float4* w4 = (const float4*)inW;
  ushort4* ow4 = (ushort4*)outW;
  for (long i = idx; i < nW4; i += stride) {
    float4 v = w4[i];
    ushort4 o;
    o.x = f2bf(v.x); o.y = f2bf(v.y); o.z = f2bf(v.z); o.w = f2bf(v.w);
    ow4[i] = o;
  }
}

// ---------------- pass 2: 256x256 bf16 GEMM, 8-phase, ONE barrier/phase -------
// CHAMPION structure (benched: GEMM ~1000us, MfmaUtil 53%, 0 conflicts):
// 8 phases = 2 K-tiles (u->buf0, v->buf1). One half-tile staged per phase;
// counted vmcnt(4) only at ph4/ph8. Read placement: ph1/ph5 head 12, ph2/ph6
// tail 8 (SCHED0-fenced post-MFMA), ph4/ph8 ahead 4 (post-vmcnt-BAR).
// THIS ROUND'S ONLY CHANGE: MFMA_QUAD loop order ks-OUTER so the two MFMAs
// accumulating into the same acc[mi][nn] are separated by 8 independent MFMAs
// (dependent-issue distance ~39cyc > MFMA latency) instead of back-to-back.
// Per-acc accumulation order unchanged (ks=0 then ks=1) -> bit-identical.
#define BAR()    __builtin_amdgcn_s_barrier()
#define SCHED0() __builtin_amdgcn_sched_barrier(0)
#define WAIT_LGKM0() do { asm volatile("s_waitcnt lgkmcnt(0)" ::: "memory"); \
                          __builtin_amdgcn_sched_barrier(0); } while (0)
#define VMCNT(N) asm volatile("s_waitcnt vmcnt(" #N ")" ::: "memory")

#define MFMA_QUAD(MQ, NP)                                                      \
  do {                                                                         \
    __builtin_amdgcn_s_setprio(1);                                             \
    _Pragma("unroll") for (int ks = 0; ks < 2; ++ks)                           \
      _Pragma("unroll") for (int mi = 0; mi < 4; ++mi)                         \
        _Pragma("unroll") for (int nn = 0; nn < 2; ++nn)                       \
          acc[(MQ)*4 + mi][(NP)*2 + nn] =                                      \
              __builtin_amdgcn_mfma_f32_16x16x32_bf16(                         \
                  af[mi][ks], bf[(NP)*2 + nn][ks],                             \
                  acc[(MQ)*4 + mi][(NP)*2 + nn], 0, 0, 0);                     \
    __builtin_amdgcn_s_setprio(0);                                             \
  } while (0)

__global__ __launch_bounds__(NTHR, 2)
void gemm256(const unsigned short* __restrict__ A,
             const unsigned short* __restrict__ W,
             const float* __restrict__ bias, float* __restrict__ C) {
  __shared__ unsigned short smA[2][BM * BK];   // 2 x 32 KiB
  __shared__ unsigned short smB[2][BN * BK];   // 2 x 32 KiB

  const int tid  = threadIdx.x;
  const int wave = tid >> 6;
  const int lane = tid & 63;
  const int wr = wave >> 2;          // 0..1  (M waves, 128 rows each)
  const int wc = wave & 3;           // 0..3  (N waves, 64 cols each)
  const int g  = lane >> 4;          // frag k-group
  const int xr = (lane & 7) << 4;    // read-side swizzle term

  int csw[2];
  csw[0] = (g * 16) ^ xr;
  csw[1] = (64 + g * 16) ^ xr;

  // XCD-aware bijective swizzle; nwg = 512 (divisible by 8)
  const int nbn = N_DIM / BN;                  // 16
  const int nwg = (M_DIM / BM) * nbn;          // 512
  const int bid = blockIdx.x;
  const int swz = (bid & 7) * (nwg >> 3) + (bid >> 3);
  const int bm = swz / nbn, bn = swz % nbn;
  const int bmBase = bm * BM, bnBase = bn * BN;

  // per-lane pre-swizzled global source offset (elements):
  // lane l -> dest row +(l>>3), 16B slot l&7 holds global slot (l&7)^((l>>3)&7)
  const size_t laneOff = (size_t)(lane >> 3) * K_DIM +
                         (size_t)(((lane & 7) ^ ((lane >> 3) & 7)) * 8);

  const unsigned short* aStage = A + (size_t)bmBase * K_DIM + laneOff;
  const unsigned short* bStage = W + (size_t)bnBase * K_DIM + laneOff;

  f32x4 acc[8][4];
  const f32x4 z = {0.f, 0.f, 0.f, 0.f};
#pragma unroll
  for (int m = 0; m < 8; ++m)
#pragma unroll
    for (int n = 0; n < 4; ++n) acc[m][n] = z;

  bf16x8 af[4][2];   // current m-quad fragments (shared slot for mq0/mq1)
  bf16x8 bf[4][2];   // all 4 n fragments (bf01 = n0:1, bf23 = n2:3)

  // stage one half-tile (16 KiB = 8 waves x 2 instr x 64 lanes x 16 B)
  auto stageHalfA = [&](int h, int buf, size_t kOff) {
#pragma unroll
    for (int j = 0; j < 2; ++j) {
      const int row0 = h * 128 + wave * 16 + j * 8;     // wave-uniform base row
      const unsigned short* src = aStage + (size_t)row0 * K_DIM + kOff;
      unsigned short* dst = &smA[buf][row0 * BK];
      __builtin_amdgcn_global_load_lds((AS1 void*)src, (AS3 void*)dst, 16, 0, 0);
    }
  };
  auto stageHalfB = [&](int h, int buf, size_t kOff) {
#pragma unroll
    for (int j = 0; j < 2; ++j) {
      const int row0 = h * 128 + wave * 16 + j * 8;
      const unsigned short* src = bStage + (size_t)row0 * K_DIM + kOff;
      unsigned short* dst = &smB[buf][row0 * BK];
      __builtin_amdgcn_global_load_lds((AS1 void*)src, (AS3 void*)dst, 16, 0, 0);
    }
  };

  const char* aRd[2] = {
      (const char*)&smA[0][0] + (wr * 128 + (lane & 15)) * 128,
      (const char*)&smA[1][0] + (wr * 128 + (lane & 15)) * 128};
  const char* bRd[2] = {
      (const char*)&smB[0][0] + (wc * 64 + (lane & 15)) * 128,
      (const char*)&smB[1][0] + (wc * 64 + (lane & 15)) * 128};

  auto readA = [&](const char* p, int mq) {
#pragma unroll
    for (int mi = 0; mi < 4; ++mi)
#pragma unroll
      for (int ks = 0; ks < 2; ++ks)
        af[mi][ks] = *(const bf16x8*)(p + (mq * 64 + mi * 16) * 128 + csw[ks]);
  };
  auto readB = [&](const char* p, int np) {
#pragma unroll
    for (int nn = 0; nn < 2; ++nn)
#pragma unroll
      for (int ks = 0; ks < 2; ++ks)
        bf[np * 2 + nn][ks] =
            *(const bf16x8*)(p + (np * 32 + nn * 16) * 128 + csw[ks]);
  };

  // one iteration = 2 K-tiles: u (buf0), v=u+1 (buf1). full=false: final iter.
  auto iter_body = [&](size_t ku, bool full) {
    const size_t kv = ku + BK, ku2 = ku + 2 * BK, kv2 = ku + 3 * BK;

    // ph1: head af0(u)+bf01(u); stage A0(v); BAR; drain; MFMA(u;0,0)
    readA(aRd[0], 0); readB(bRd[0], 0);            // 12 ds_reads
    stageHalfA(0, 1, kv);
    BAR(); WAIT_LGKM0();
    MFMA_QUAD(0, 0);

    // ph2: stage A1(v); BAR; MFMA(u;0,1); tail af1(u)
    stageHalfA(1, 1, kv);
    BAR(); SCHED0();
    MFMA_QUAD(0, 1);
    SCHED0();
    readA(aRd[0], 1);                              // 8 ds_reads (tail)

    // ph3: stage B0(u+2); BAR; drain ph2-tail; MFMA(u;1,1)
    if (full) stageHalfB(0, 0, ku2);
    BAR(); WAIT_LGKM0();
    MFMA_QUAD(1, 1);

    // ph4: stage B1(u+2); vmcnt(4) -> tile v resident; BAR; ahead bf23(v);
    //      MFMA(u;1,0)
    if (full) {
      stageHalfB(1, 0, ku2);
      VMCNT(4);
    } else {
      VMCNT(0);
    }
    BAR(); SCHED0();
    readB(bRd[1], 1);                              // 4 ds_reads (ahead, dead slot)
    MFMA_QUAD(1, 0);

    // ph5: head af0(v)+bf01(v); stage A0(u+2); BAR; drain; MFMA(v;0,0)
    readA(aRd[1], 0); readB(bRd[1], 0);
    if (full) stageHalfA(0, 0, ku2);
    BAR(); WAIT_LGKM0();
    MFMA_QUAD(0, 0);

    // ph6: stage A1(u+2); BAR; MFMA(v;0,1); tail af1(v)
    if (full) stageHalfA(1, 0, ku2);
    BAR(); SCHED0();
    MFMA_QUAD(0, 1);
    SCHED0();
    readA(aRd[1], 1);

    // ph7: stage B0(v+2); BAR; drain ph6-tail; MFMA(v;1,1)
    if (full) stageHalfB(0, 1, kv2);
    BAR(); WAIT_LGKM0();
    MFMA_QUAD(1, 1);

    // ph8: stage B1(v+2); vmcnt(4) -> tile u+2 resident; BAR; ahead bf23(u+2);
    //      MFMA(v;1,0)
    if (full) {
      stageHalfB(1, 1, kv2);
      VMCNT(4);
    }
    BAR(); SCHED0();
    if (full) readB(bRd[0], 1);                    // bf23(u+2) for next ph2
    MFMA_QUAD(1, 0);
  };

  // ---- prologue: 6 half-tiles; vmcnt(4) -> tile0 resident, B(1) in flight ----
  stageHalfB(0, 0, 0); stageHalfB(1, 0, 0);
  stageHalfA(0, 0, 0); stageHalfA(1, 0, 0);
  stageHalfB(0, 1, BK); stageHalfB(1, 1, BK);
  VMCNT(4);
  BAR(); SCHED0();
  readB(bRd[0], 1);                 // bf23(tile0): the "prev-ph8" ahead-read

  size_t ku = 0;
  for (int J = 0; J < K_TILES / 2 - 1; ++J) {   // 127 steady iterations
    iter_body(ku, true);
    ku += 2 * BK;
  }
  iter_body(ku, false);                          // tiles 254,255: drain

  // ---- epilogue: C = acc + bias. C/D layout: col=lane&15, row=(lane>>4)*4+j
  const int crow0 = bmBase + wr * 128 + ((lane >> 4) << 2);
  const int ccol0 = bnBase + wc * 64 + (lane & 15);
#pragma unroll
  for (int n = 0; n < 4; ++n) {
    const float bv = bias[ccol0 + n * 16];
#pragma unroll
    for (int mi = 0; mi < 8; ++mi) {
      const size_t base = (size_t)(crow0 + mi * 16) * N_DIM + (ccol0 + n * 16);
#pragma unroll
      for (int j = 0; j < 4; ++j)
        C[base + (size_t)j * N_DIM] = acc[mi][n][j] + bv;
    }
  }
}

// ---------------- fallback: fused-cvt 128x128 GEMM (ws too small) -------------
__global__ __launch_bounds__(256)
void gemm_fallback(const float* __restrict__ Af, const float* __restrict__ Wf,
                   const float* __restrict__ bias, float* __restrict__ C) {
  __shared__ __align__(16) unsigned short sA[128 * 64];
  __shared__ __align__(16) unsigned short sB[128 * 64];
  const int tid = threadIdx.x, wave = tid >> 6, lane = tid & 63;
  const int wr = wave >> 1, wc = wave & 1;
  const int nbn = N_DIM / 128, nwg = (M_DIM / 128) * nbn;
  const int swz = (blockIdx.x & 7) * (nwg >> 3) + (blockIdx.x >> 3);
  const int bm = swz / nbn, bn = swz % nbn;
  f32x4 acc[4][4];
  const f32x4 z = {0.f, 0.f, 0.f, 0.f};
#pragma unroll
  for (int m = 0; m < 4; ++m)
#pragma unroll
    for (int n = 0; n < 4; ++n) acc[m][n] = z;
  for (int kt = 0; kt < K_DIM / 64; ++kt) {
    const int k0 = kt * 64;
    const int row2 = tid >> 1, ch = (tid & 1) * 32;
    const float* sa = Af + (size_t)(bm * 128 + row2) * K_DIM + k0 + ch;
    const float* sb = Wf + (size_t)(bn * 128 + row2) * K_DIM + k0 + ch;
    unsigned short* da = sA + row2 * 64 + ch;
    unsigned short* db = sB + row2 * 64 + ch;
#pragma unroll
    for (int j = 0; j < 8; ++j) {
      float4 v = *(const float4*)(sa + j * 4);
      ushort4 o; o.x = f2bf(v.x); o.y = f2bf(v.y); o.z = f2bf(v.z); o.w = f2bf(v.w);
      *(ushort4*)(da + j * 4) = o;
      float4 w = *(const float4*)(sb + j * 4);
      ushort4 p; p.x = f2bf(w.x); p.y = f2bf(w.y); p.z = f2bf(w.z); p.w = f2bf(w.w);
      *(ushort4*)(db + j * 4) = p;
    }
    __syncthreads();
#pragma unroll
    for (int ks = 0; ks < 2; ++ks) {
      bf16x8 a4[4], b4[4];
#pragma unroll
      for (int m = 0; m < 4; ++m)
        a4[m] = *(const bf16x8*)(sA + (wr * 64 + m * 16 + (lane & 15)) * 64 +
                                 ks * 32 + (lane >> 4) * 8);
#pragma unroll
      for (int n = 0; n < 4; ++n)
        b4[n] = *(const bf16x8*)(sB + (wc * 64 + n * 16 + (lane & 15)) * 64 +
                                 ks * 32 + (lane >> 4) * 8);
#pragma unroll
      for (int m = 0; m < 4; ++m)
#pragma unroll
        for (int n = 0; n < 4; ++n)
          acc[m][n] = __builtin_amdgcn_mfma_f32_16x16x32_bf16(a4[m], b4[n],
                                                              acc[m][n], 0, 0, 0);
    }
    __syncthreads();
  }
  const int crow = bm * 128 + wr * 64 + ((lane >> 4) << 2);
  const int ccol = bn * 128 + wc * 64 + (lane & 15);
#pragma unroll
  for (int n = 0; n < 4; ++n) {
    const float bv = bias[ccol + n * 16];
#pragma unroll
    for (int m = 0; m < 4; ++m) {
      const size_t base = (size_t)(crow + m * 16) * N_DIM + (ccol + n * 16);
#pragma unroll
      for (int j = 0; j < 4; ++j) C[base + (size_t)j * N_DIM] = acc[m][n][j] + bv;
    }
  }
}

// ------------------------------ launcher --------------------------------------
extern "C" void kernel_launch(void* const* d_in, const int* in_sizes, int n_in,
                              void* d_out, int out_size, void* d_ws, size_t ws_size,
                              hipStream_t stream) {
  const float* A    = (const float*)d_in[0];   // [8192, 16384] fp32
  const float* Wt   = (const float*)d_in[1];   // [4096, 16384] fp32
  const float* bias = (const float*)d_in[2];   // [4096] fp32
  float* out = (float*)d_out;                  // [8192, 4096] fp32

  const size_t elemsA = (size_t)M_DIM * K_DIM;
  const size_t elemsW = (size_t)N_DIM * K_DIM;
  const size_t need = (elemsA + elemsW) * sizeof(unsigned short);  // 384 MiB

  if (ws_size >= need) {
    unsigned short* wsA = (unsigned short*)d_ws;
    unsigned short* wsW = wsA + elemsA;
    cvt2_f32_bf16<<<2048, 256, 0, stream>>>(A, wsA, (long)(elemsA / 4),
                                            Wt, wsW, (long)(elemsW / 4));
    const int ngrid = (M_DIM / BM) * (N_DIM / BN);  // 512
    gemm256<<<ngrid, NTHR, 0, stream>>>(wsA, wsW, bias, out);
  } else {
    const int ngrid = (M_DIM / 128) * (N_DIM / 128);
    gemm_fallback<<<ngrid, 256, 0, stream>>>(A, Wt, bias, out);
  }
}

// Round 11
// 1130.079 us; speedup vs baseline: 10.2408x; 1.0009x over previous
//
#include <hip/hip_runtime.h>
#include <stdint.h>
#include <stddef.h>

// Row-parallel linear: C[M][N] = A[M][K] * W[N][K]^T + bias
// M = SEQ*BATCH = 8192, N = D_MODEL = 4096, K = D_FF = 16384
#define M_DIM 8192
#define N_DIM 4096
#define K_DIM 16384

#define BM 256
#define BN 256
#define BK 64
#define NTHR 512                  // 8 waves: 2 (M) x 4 (N)
#define K_TILES (K_DIM / BK)      // 256

typedef __attribute__((ext_vector_type(8))) short bf16x8;   // 8 bf16 = 4 VGPRs
typedef __attribute__((ext_vector_type(4))) float f32x4;    // MFMA C/D

#define AS1 __attribute__((address_space(1)))
#define AS3 __attribute__((address_space(3)))

__device__ __forceinline__ unsigned short f2bf(float f) {
  union { float f; unsigned u; } x; x.f = f;
  unsigned r = x.u + 0x7fffu + ((x.u >> 16) & 1u);
  return (unsigned short)(r >> 16);
}

// ------------- pass 1: fused fp32 -> bf16 conversion (A then W) ---------------
__global__ void cvt2_f32_bf16(const float* __restrict__ inA,
                              unsigned short* __restrict__ outA, long nA4,
                              const float* __restrict__ inW,
                              unsigned short* __restrict__ outW, long nW4) {
  long idx = (long)blockIdx.x * blockDim.x + threadIdx.x;
  long stride = (long)gridDim.x * blockDim.x;
  const float4* a4 = (const float4*)inA;
  ushort4* oa4 = (ushort4*)outA;
  for (long i = idx; i < nA4; i += stride) {
    float4 v = a4[i];
    ushort4 o;
    o.x = f2bf(v.x); o.y = f2bf(v.y); o.z = f2bf(v.z); o.w = f2bf(v.w);
    oa4[i] = o;
  }
  const float4* w4 = (const float4*)inW;
  ushort4* ow4 = (ushort4*)outW;
  for (long i = idx; i < nW4; i += stride) {
    float4 v = w4[i];
    ushort4 o;
    o.x = f2bf(v.x); o.y = f2bf(v.y); o.z = f2bf(v.z); o.w = f2bf(v.w);
    ow4[i] = o;
  }
}

// ---------------- pass 2: 256x256 bf16 GEMM, 8-phase, ONE barrier/phase -------
// Champion structure (GEMM ~1000us, MfmaUtil 53%, 0 conflicts). THIS ROUND:
// fences relaxed a la m201 — lgkmcnt(0)/vmcnt asm keep their "memory" clobber
// (memory-op ordering for cross-wave WAR/RAW certification is unchanged:
// ds_read/global_load_lds cannot cross the asm or s_barrier), but no
// sched_barrier after them: pure register ops (MFMA) may hoist, so the
// compiler schedules each MFMA behind its own partial lgkmcnt(N) instead of
// stalling the whole cluster behind the full drain. SCHED0 retained ONLY
// before the ph2/ph6 tail reads (pins af overwrite after its consumers,
// avoiding register-rename pressure -> r9-style spill).
#define BAR()    __builtin_amdgcn_s_barrier()
#define SCHED0() __builtin_amdgcn_sched_barrier(0)
#define WAIT_LGKM0() asm volatile("s_waitcnt lgkmcnt(0)" ::: "memory")
#define VMCNT(N) asm volatile("s_waitcnt vmcnt(" #N ")" ::: "memory")

#define MFMA_QUAD(MQ, NP)                                                      \
  do {                                                                         \
    __builtin_amdgcn_s_setprio(1);                                             \
    _Pragma("unroll") for (int ks = 0; ks < 2; ++ks)                           \
      _Pragma("unroll") for (int mi = 0; mi < 4; ++mi)                         \
        _Pragma("unroll") for (int nn = 0; nn < 2; ++nn)                       \
          acc[(MQ)*4 + mi][(NP)*2 + nn] =                                      \
              __builtin_amdgcn_mfma_f32_16x16x32_bf16(                         \
                  af[mi][ks], bf[(NP)*2 + nn][ks],                             \
                  acc[(MQ)*4 + mi][(NP)*2 + nn], 0, 0, 0);                     \
    __builtin_amdgcn_s_setprio(0);                                             \
  } while (0)

__global__ __launch_bounds__(NTHR, 2)
void gemm256(const unsigned short* __restrict__ A,
             const unsigned short* __restrict__ W,
             const float* __restrict__ bias, float* __restrict__ C) {
  __shared__ unsigned short smA[2][BM * BK];   // 2 x 32 KiB
  __shared__ unsigned short smB[2][BN * BK];   // 2 x 32 KiB

  const int tid  = threadIdx.x;
  const int wave = tid >> 6;
  const int lane = tid & 63;
  const int wr = wave >> 2;          // 0..1  (M waves, 128 rows each)
  const int wc = wave & 3;           // 0..3  (N waves, 64 cols each)
  const int g  = lane >> 4;          // frag k-group
  const int xr = (lane & 7) << 4;    // read-side swizzle term

  int csw[2];
  csw[0] = (g * 16) ^ xr;
  csw[1] = (64 + g * 16) ^ xr;

  // XCD-aware bijective swizzle; nwg = 512 (divisible by 8)
  const int nbn = N_DIM / BN;                  // 16
  const int nwg = (M_DIM / BM) * nbn;          // 512
  const int bid = blockIdx.x;
  const int swz = (bid & 7) * (nwg >> 3) + (bid >> 3);
  const int bm = swz / nbn, bn = swz % nbn;
  const int bmBase = bm * BM, bnBase = bn * BN;

  // per-lane pre-swizzled global source offset (elements):
  // lane l -> dest row +(l>>3), 16B slot l&7 holds global slot (l&7)^((l>>3)&7)
  const size_t laneOff = (size_t)(lane >> 3) * K_DIM +
                         (size_t)(((lane & 7) ^ ((lane >> 3) & 7)) * 8);

  const unsigned short* aStage = A + (size_t)bmBase * K_DIM + laneOff;
  const unsigned short* bStage = W + (size_t)bnBase * K_DIM + laneOff;

  f32x4 acc[8][4];
  const f32x4 z = {0.f, 0.f, 0.f, 0.f};
#pragma unroll
  for (int m = 0; m < 8; ++m)
#pragma unroll
    for (int n = 0; n < 4; ++n) acc[m][n] = z;

  bf16x8 af[4][2];   // current m-quad fragments (shared slot for mq0/mq1)
  bf16x8 bf[4][2];   // all 4 n fragments (bf01 = n0:1, bf23 = n2:3)

  // stage one half-tile (16 KiB = 8 waves x 2 instr x 64 lanes x 16 B)
  auto stageHalfA = [&](int h, int buf, size_t kOff) {
#pragma unroll
    for (int j = 0; j < 2; ++j) {
      const int row0 = h * 128 + wave * 16 + j * 8;     // wave-uniform base row
      const unsigned short* src = aStage + (size_t)row0 * K_DIM + kOff;
      unsigned short* dst = &smA[buf][row0 * BK];
      __builtin_amdgcn_global_load_lds((AS1 void*)src, (AS3 void*)dst, 16, 0, 0);
    }
  };
  auto stageHalfB = [&](int h, int buf, size_t kOff) {
#pragma unroll
    for (int j = 0; j < 2; ++j) {
      const int row0 = h * 128 + wave * 16 + j * 8;
      const unsigned short* src = bStage + (size_t)row0 * K_DIM + kOff;
      unsigned short* dst = &smB[buf][row0 * BK];
      __builtin_amdgcn_global_load_lds((AS1 void*)src, (AS3 void*)dst, 16, 0, 0);
    }
  };

  const char* aRd[2] = {
      (const char*)&smA[0][0] + (wr * 128 + (lane & 15)) * 128,
      (const char*)&smA[1][0] + (wr * 128 + (lane & 15)) * 128};
  const char* bRd[2] = {
      (const char*)&smB[0][0] + (wc * 64 + (lane & 15)) * 128,
      (const char*)&smB[1][0] + (wc * 64 + (lane & 15)) * 128};

  auto readA = [&](const char* p, int mq) {
#pragma unroll
    for (int mi = 0; mi < 4; ++mi)
#pragma unroll
      for (int ks = 0; ks < 2; ++ks)
        af[mi][ks] = *(const bf16x8*)(p + (mq * 64 + mi * 16) * 128 + csw[ks]);
  };
  auto readB = [&](const char* p, int np) {
#pragma unroll
    for (int nn = 0; nn < 2; ++nn)
#pragma unroll
      for (int ks = 0; ks < 2; ++ks)
        bf[np * 2 + nn][ks] =
            *(const bf16x8*)(p + (np * 32 + nn * 16) * 128 + csw[ks]);
  };

  // one iteration = 2 K-tiles: u (buf0), v=u+1 (buf1). full=false: final iter.
  auto iter_body = [&](size_t ku, bool full) {
    const size_t kv = ku + BK, ku2 = ku + 2 * BK, kv2 = ku + 3 * BK;

    // ph1: head af0(u)+bf01(u); stage A0(v); BAR; drain; MFMA(u;0,0)
    readA(aRd[0], 0); readB(bRd[0], 0);            // 12 ds_reads
    stageHalfA(0, 1, kv);
    BAR(); WAIT_LGKM0();
    MFMA_QUAD(0, 0);

    // ph2: stage A1(v); BAR; MFMA(u;0,1); tail af1(u)
    stageHalfA(1, 1, kv);
    BAR();
    MFMA_QUAD(0, 1);
    SCHED0();
    readA(aRd[0], 1);                              // 8 ds_reads (tail)

    // ph3: stage B0(u+2); BAR; drain ph2-tail; MFMA(u;1,1)
    if (full) stageHalfB(0, 0, ku2);
    BAR(); WAIT_LGKM0();
    MFMA_QUAD(1, 1);

    // ph4: stage B1(u+2); vmcnt(4) -> tile v resident; BAR; ahead bf23(v);
    //      MFMA(u;1,0)
    if (full) {
      stageHalfB(1, 0, ku2);
      VMCNT(4);
    } else {
      VMCNT(0);
    }
    BAR();
    readB(bRd[1], 1);                              // 4 ds_reads (ahead, dead slot)
    MFMA_QUAD(1, 0);

    // ph5: head af0(v)+bf01(v); stage A0(u+2); BAR; drain; MFMA(v;0,0)
    readA(aRd[1], 0); readB(bRd[1], 0);
    if (full) stageHalfA(0, 0, ku2);
    BAR(); WAIT_LGKM0();
    MFMA_QUAD(0, 0);

    // ph6: stage A1(u+2); BAR; MFMA(v;0,1); tail af1(v)
    if (full) stageHalfA(1, 0, ku2);
    BAR();
    MFMA_QUAD(0, 1);
    SCHED0();
    readA(aRd[1], 1);

    // ph7: stage B0(v+2); BAR; drain ph6-tail; MFMA(v;1,1)
    if (full) stageHalfB(0, 1, kv2);
    BAR(); WAIT_LGKM0();
    MFMA_QUAD(1, 1);

    // ph8: stage B1(v+2); vmcnt(4) -> tile u+2 resident; BAR; ahead bf23(u+2);
    //      MFMA(v;1,0)
    if (full) {
      stageHalfB(1, 1, kv2);
      VMCNT(4);
    }
    BAR();
    if (full) readB(bRd[0], 1);                    // bf23(u+2) for next ph2
    MFMA_QUAD(1, 0);
  };

  // ---- prologue: 6 half-tiles; vmcnt(4) -> tile0 resident, B(1) in flight ----
  stageHalfB(0, 0, 0); stageHalfB(1, 0, 0);
  stageHalfA(0, 0, 0); stageHalfA(1, 0, 0);
  stageHalfB(0, 1, BK); stageHalfB(1, 1, BK);
  VMCNT(4);
  BAR();
  readB(bRd[0], 1);                 // bf23(tile0): the "prev-ph8" ahead-read

  size_t ku = 0;
  for (int J = 0; J < K_TILES / 2 - 1; ++J) {   // 127 steady iterations
    iter_body(ku, true);
    ku += 2 * BK;
  }
  iter_body(ku, false);                          // tiles 254,255: drain

  // ---- epilogue: C = acc + bias. C/D layout: col=lane&15, row=(lane>>4)*4+j
  const int crow0 = bmBase + wr * 128 + ((lane >> 4) << 2);
  const int ccol0 = bnBase + wc * 64 + (lane & 15);
#pragma unroll
  for (int n = 0; n < 4; ++n) {
    const float bv = bias[ccol0 + n * 16];
#pragma unroll
    for (int mi = 0; mi < 8; ++mi) {
      const size_t base = (size_t)(crow0 + mi * 16) * N_DIM + (ccol0 + n * 16);
#pragma unroll
      for (int j = 0; j < 4; ++j)
        C[base + (size_t)j * N_DIM] = acc[mi][n][j] + bv;
    }
  }
}

// ---------------- fallback: fused-cvt 128x128 GEMM (ws too small) -------------
__global__ __launch_bounds__(256)
void gemm_fallback(const float* __restrict__ Af, const float* __restrict__ Wf,
                   const float* __restrict__ bias, float* __restrict__ C) {
  __shared__ __align__(16) unsigned short sA[128 * 64];
  __shared__ __align__(16) unsigned short sB[128 * 64];
  const int tid = threadIdx.x, wave = tid >> 6, lane = tid & 63;
  const int wr = wave >> 1, wc = wave & 1;
  const int nbn = N_DIM / 128, nwg = (M_DIM / 128) * nbn;
  const int swz = (blockIdx.x & 7) * (nwg >> 3) + (blockIdx.x >> 3);
  const int bm = swz / nbn, bn = swz % nbn;
  f32x4 acc[4][4];
  const f32x4 z = {0.f, 0.f, 0.f, 0.f};
#pragma unroll
  for (int m = 0; m < 4; ++m)
#pragma unroll
    for (int n = 0; n < 4; ++n) acc[m][n] = z;
  for (int kt = 0; kt < K_DIM / 64; ++kt) {
    const int k0 = kt * 64;
    const int row2 = tid >> 1, ch = (tid & 1) * 32;
    const float* sa = Af + (size_t)(bm * 128 + row2) * K_DIM + k0 + ch;
    const float* sb = Wf + (size_t)(bn * 128 + row2) * K_DIM + k0 + ch;
    unsigned short* da = sA + row2 * 64 + ch;
    unsigned short* db = sB + row2 * 64 + ch;
#pragma unroll
    for (int j = 0; j < 8; ++j) {
      float4 v = *(const float4*)(sa + j * 4);
      ushort4 o; o.x = f2bf(v.x); o.y = f2bf(v.y); o.z = f2bf(v.z); o.w = f2bf(v.w);
      *(ushort4*)(da + j * 4) = o;
      float4 w = *(const float4*)(sb + j * 4);
      ushort4 p; p.x = f2bf(w.x); p.y = f2bf(w.y); p.z = f2bf(w.z); p.w = f2bf(w.w);
      *(ushort4*)(db + j * 4) = p;
    }
    __syncthreads();
#pragma unroll
    for (int ks = 0; ks < 2; ++ks) {
      bf16x8 a4[4], b4[4];
#pragma unroll
      for (int m = 0; m < 4; ++m)
        a4[m] = *(const bf16x8*)(sA + (wr * 64 + m * 16 + (lane & 15)) * 64 +
                                 ks * 32 + (lane >> 4) * 8);
#pragma unroll
      for (int n = 0; n < 4; ++n)
        b4[n] = *(const bf16x8*)(sB + (wc * 64 + n * 16 + (lane & 15)) * 64 +
                                 ks * 32 + (lane >> 4) * 8);
#pragma unroll
      for (int m = 0; m < 4; ++m)
#pragma unroll
        for (int n = 0; n < 4; ++n)
          acc[m][n] = __builtin_amdgcn_mfma_f32_16x16x32_bf16(a4[m], b4[n],
                                                              acc[m][n], 0, 0, 0);
    }
    __syncthreads();
  }
  const int crow = bm * 128 + wr * 64 + ((lane >> 4) << 2);
  const int ccol = bn * 128 + wc * 64 + (lane & 15);
#pragma unroll
  for (int n = 0; n < 4; ++n) {
    const float bv = bias[ccol + n * 16];
#pragma unroll
    for (int m = 0; m < 4; ++m) {
      const size_t base = (size_t)(crow + m * 16) * N_DIM + (ccol + n * 16);
#pragma unroll
      for (int j = 0; j < 4; ++j) C[base + (size_t)j * N_DIM] = acc[m][n][j] + bv;
    }
  }
}

// ------------------------------ launcher --------------------------------------
extern "C" void kernel_launch(void* const* d_in, const int* in_sizes, int n_in,
                              void* d_out, int out_size, void* d_ws, size_t ws_size,
                              hipStream_t stream) {
  const float* A    = (const float*)d_in[0];   // [8192, 16384] fp32
  const float* Wt   = (const float*)d_in[1];   // [4096, 16384] fp32
  const float* bias = (const float*)d_in[2];   // [4096] fp32
  float* out = (float*)d_out;                  // [8192, 4096] fp32

  const size_t elemsA = (size_t)M_DIM * K_DIM;
  const size_t elemsW = (size_t)N_DIM * K_DIM;
  const size_t need = (elemsA + elemsW) * sizeof(unsigned short);  // 384 MiB

  if (ws_size >= need) {
    unsigned short* wsA = (unsigned short*)d_ws;
    unsigned short* wsW = wsA + elemsA;
    cvt2_f32_bf16<<<2048, 256, 0, stream>>>(A, wsA, (long)(elemsA / 4),
                                            Wt, wsW, (long)(elemsW / 4));
    const int ngrid = (M_DIM / BM) * (N_DIM / BN);  // 512
    gemm256<<<ngrid, NTHR, 0, stream>>>(wsA, wsW, bias, out);
  } else {
    const int ngrid = (M_DIM / 128) * (N_DIM / 128);
    gemm_fallback<<<ngrid, 256, 0, stream>>>(A, Wt, bias, out);
  }
}